// Round 1
// baseline (251.444 us; speedup 1.0000x reference)
//
#include <hip/hip_runtime.h>

// LocalNetwork: B=256, x (B,15,64,128,1) f32.
// Downsample mean(3,4,4) -> (5,16,32); depth/lon/lat flat local conv3+relu; upsample broadcast.
// One block per batch item; whole per-batch pipeline lives in LDS.

#define THREADS 1024
#define NELEM   (15 * 64 * 128)   // 122880 floats per batch item

__global__ __launch_bounds__(THREADS) void localnet_kernel(
    const float* __restrict__ x,
    const float* __restrict__ w_depth, const float* __restrict__ b_depth,
    const float* __restrict__ w_lon,   const float* __restrict__ b_lon,
    const float* __restrict__ w_lat,   const float* __restrict__ b_lat,
    float* __restrict__ out)
{
    const int b   = blockIdx.x;
    const int tid = threadIdx.x;

    // bufA: padded input to each conv (max 3586 = depth stage)
    // bufB: conv outputs (max 3584)
    __shared__ float bufA[3586];
    __shared__ float bufB[3584];

    const float* xb = x   + (size_t)b * NELEM;
    float*       ob = out + (size_t)b * NELEM;

    // ---- zero padded depth buffer (covers flat pads + depth pads k=0,6) ----
    for (int i = tid; i < 3586; i += THREADS) bufA[i] = 0.f;
    __syncthreads();

    // ---- stage 1: 3x4x4 mean downsample, scatter into depth-flat layout ----
    // cell c -> (id, ih, iw); flat depth index j = ((iw*16+ih)*7 + (id+1)), +1 flat pad
    for (int c = tid; c < 2560; c += THREADS) {
        const int iw = c & 31;
        const int ih = (c >> 5) & 15;
        const int id = c >> 9;                   // 0..4
        const float* p = xb + ((id * 3) * 64 + ih * 4) * 128 + iw * 4;
        float s = 0.f;
        #pragma unroll
        for (int dd = 0; dd < 3; ++dd) {
            #pragma unroll
            for (int hh = 0; hh < 4; ++hh) {
                const float4 v = *reinterpret_cast<const float4*>(p + (dd * 64 + hh) * 128);
                s += (v.x + v.y) + (v.z + v.w);
            }
        }
        bufA[1 + ((iw * 16 + ih) * 7 + (id + 1))] = s * (1.f / 48.f);
    }
    __syncthreads();

    // ---- depth conv3 + relu (L_DEPTH = 3584) ----
    for (int l = tid; l < 3584; l += THREADS) {
        float y = w_depth[l * 3 + 0] * bufA[l]
                + w_depth[l * 3 + 1] * bufA[l + 1]
                + w_depth[l * 3 + 2] * bufA[l + 2]
                + b_depth[l];
        bufB[l] = fmaxf(y, 0.f);
    }
    __syncthreads();

    // ---- build lon padded flat (len 2722) from depth output ----
    // lon flat l: k = l%34 (w+pad), ih = (l/34)%16, dep = l/(34*16)
    // depth result (sliced to dep 0..4): td2[dep][ih][iw] = bufB[((iw*16+ih)*7 + dep+1)]
    for (int i = tid; i < 2722; i += THREADS) {
        float v = 0.f;
        if (i >= 1 && i <= 2720) {
            const int l   = i - 1;
            const int k   = l % 34;
            const int ih  = (l / 34) & 15;
            const int dep = l / (34 * 16);
            if (k >= 1 && k <= 32)
                v = bufB[((k - 1) * 16 + ih) * 7 + dep + 1];
        }
        bufA[i] = v;
    }
    __syncthreads();

    // ---- lon conv3 + relu (L_LON = 2720) ----
    for (int l = tid; l < 2720; l += THREADS) {
        float y = w_lon[l * 3 + 0] * bufA[l]
                + w_lon[l * 3 + 1] * bufA[l + 1]
                + w_lon[l * 3 + 2] * bufA[l + 2]
                + b_lon[l];
        bufB[l] = fmaxf(y, 0.f);
    }
    __syncthreads();

    // ---- build lat padded flat (len 2882) from lon output ----
    // lat flat l: k = l%18 (h+pad), iw = (l/18)%32, dep = l/(18*32)
    // lon result (sliced to iw 0..31): u2[dep][ih][iw] = bufB[(dep*16+ih)*34 + iw+1]
    for (int i = tid; i < 2882; i += THREADS) {
        float v = 0.f;
        if (i >= 1 && i <= 2880) {
            const int l   = i - 1;
            const int k   = l % 18;
            const int iw  = (l / 18) & 31;
            const int dep = l / (18 * 32);
            if (k >= 1 && k <= 16)
                v = bufB[(dep * 16 + (k - 1)) * 34 + iw + 1];
        }
        bufA[i] = v;
    }
    __syncthreads();

    // ---- lat conv3 + relu (L_LAT = 2880) ----
    for (int l = tid; l < 2880; l += THREADS) {
        float y = w_lat[l * 3 + 0] * bufA[l]
                + w_lat[l * 3 + 1] * bufA[l + 1]
                + w_lat[l * 3 + 2] * bufA[l + 2]
                + b_lat[l];
        bufB[l] = fmaxf(y, 0.f);
    }
    __syncthreads();

    // ---- upsample broadcast + float4 store ----
    // out[Din][Hin][Win] = v2[Din/3][Hin/4][Win/4];
    // v2[dep][ihh][iww] = bufB[(dep*32+iww)*18 + ihh + 1]
    for (int o = tid; o < 30720; o += THREADS) {   // 30720 float4 per batch item
        const int iw4 = o & 31;
        const int Hin = (o >> 5) & 63;
        const int Din = o >> 11;
        const float v = bufB[((Din / 3) * 32 + iw4) * 18 + (Hin >> 2) + 1];
        *reinterpret_cast<float4*>(ob + (size_t)o * 4) = make_float4(v, v, v, v);
    }
}

extern "C" void kernel_launch(void* const* d_in, const int* in_sizes, int n_in,
                              void* d_out, int out_size, void* d_ws, size_t ws_size,
                              hipStream_t stream) {
    const float* x       = (const float*)d_in[0];
    const float* w_depth = (const float*)d_in[1];
    const float* b_depth = (const float*)d_in[2];
    const float* w_lon   = (const float*)d_in[3];
    const float* b_lon   = (const float*)d_in[4];
    const float* w_lat   = (const float*)d_in[5];
    const float* b_lat   = (const float*)d_in[6];
    float* out = (float*)d_out;

    const int Bn = in_sizes[0] / NELEM;   // 256
    localnet_kernel<<<dim3(Bn), dim3(THREADS), 0, stream>>>(
        x, w_depth, b_depth, w_lon, b_lon, w_lat, b_lat, out);
}

// Round 2
// 250.146 us; speedup vs baseline: 1.0052x; 1.0052x over previous
//
#include <hip/hip_runtime.h>

// LocalNetwork split into 3 kernels:
//  K1: 3x4x4 mean downsample  (HBM read-bound, 126 MB)
//  K2: depth/lon/lat conv3+relu pipeline in LDS (tiny, L2-bound)
//  K3: broadcast upsample     (HBM write-bound, 126 MB)

#define NELEM   (15 * 64 * 128)   // 122880 floats per batch item
#define NCELL   2560              // 5*16*32 downsampled cells per item
#define NQ      30720             // float4 stores per item (122880/4)

// ---------------- K1: downsample ----------------
// ds[b*2560 + c], c = (id*16+ih)*32+iw  (iw fastest -> coalesced)
__global__ __launch_bounds__(256) void k_down(const float* __restrict__ x,
                                              float* __restrict__ ds)
{
    const int idx = blockIdx.x * 256 + threadIdx.x;     // 0 .. B*2560-1
    const int b   = idx >> 11 >> 0;                     // idx / 2560 below
    // idx = b*2560 + c
    const int bb  = idx / NCELL;
    const int c   = idx - bb * NCELL;
    const int iw  = c & 31;
    const int ih  = (c >> 5) & 15;
    const int id  = c >> 9;

    const float* p = x + (size_t)bb * NELEM + ((id * 3) * 64 + ih * 4) * 128 + iw * 4;
    float s = 0.f;
    #pragma unroll
    for (int dd = 0; dd < 3; ++dd) {
        #pragma unroll
        for (int hh = 0; hh < 4; ++hh) {
            const float4 v = *reinterpret_cast<const float4*>(p + (dd * 64 + hh) * 128);
            s += (v.x + v.y) + (v.z + v.w);
        }
    }
    ds[idx] = s * (1.f / 48.f);
    (void)b;
}

// ---------------- K2: conv pipeline ----------------
// reads ds[b][.], writes v2[b][(dep*16+ihh)*32+iww]
__global__ __launch_bounds__(256) void k_conv(
    const float* __restrict__ ds,
    const float* __restrict__ w_depth, const float* __restrict__ b_depth,
    const float* __restrict__ w_lon,   const float* __restrict__ b_lon,
    const float* __restrict__ w_lat,   const float* __restrict__ b_lat,
    float* __restrict__ v2)
{
    const int b   = blockIdx.x;
    const int tid = threadIdx.x;
    __shared__ float bufA[3586];
    __shared__ float bufB[3584];

    for (int i = tid; i < 3586; i += 256) bufA[i] = 0.f;
    __syncthreads();

    // scatter ds into depth-flat padded layout: bufA[1 + (iw*16+ih)*7 + id+1]
    for (int c = tid; c < NCELL; c += 256) {
        const int iw = c & 31;
        const int ih = (c >> 5) & 15;
        const int id = c >> 9;
        bufA[1 + ((iw * 16 + ih) * 7 + id + 1)] = ds[(size_t)b * NCELL + c];
    }
    __syncthreads();

    // depth conv3+relu (L=3584)
    for (int l = tid; l < 3584; l += 256) {
        float y = w_depth[l * 3 + 0] * bufA[l]
                + w_depth[l * 3 + 1] * bufA[l + 1]
                + w_depth[l * 3 + 2] * bufA[l + 2]
                + b_depth[l];
        bufB[l] = fmaxf(y, 0.f);
    }
    __syncthreads();

    // build lon padded flat (2722)
    for (int i = tid; i < 2722; i += 256) {
        float v = 0.f;
        if (i >= 1 && i <= 2720) {
            const int l   = i - 1;
            const int k   = l % 34;
            const int ih  = (l / 34) & 15;
            const int dep = l / (34 * 16);
            if (k >= 1 && k <= 32)
                v = bufB[((k - 1) * 16 + ih) * 7 + dep + 1];
        }
        bufA[i] = v;
    }
    __syncthreads();

    // lon conv3+relu (L=2720)
    for (int l = tid; l < 2720; l += 256) {
        float y = w_lon[l * 3 + 0] * bufA[l]
                + w_lon[l * 3 + 1] * bufA[l + 1]
                + w_lon[l * 3 + 2] * bufA[l + 2]
                + b_lon[l];
        bufB[l] = fmaxf(y, 0.f);
    }
    __syncthreads();

    // build lat padded flat (2882)
    for (int i = tid; i < 2882; i += 256) {
        float v = 0.f;
        if (i >= 1 && i <= 2880) {
            const int l   = i - 1;
            const int k   = l % 18;
            const int iw  = (l / 18) & 31;
            const int dep = l / (18 * 32);
            if (k >= 1 && k <= 16)
                v = bufB[(dep * 16 + (k - 1)) * 34 + iw + 1];
        }
        bufA[i] = v;
    }
    __syncthreads();

    // lat conv3+relu (L=2880)
    for (int l = tid; l < 2880; l += 256) {
        float y = w_lat[l * 3 + 0] * bufA[l]
                + w_lat[l * 3 + 1] * bufA[l + 1]
                + w_lat[l * 3 + 2] * bufA[l + 2]
                + b_lat[l];
        bufB[l] = fmaxf(y, 0.f);
    }
    __syncthreads();

    // export v2: c = (dep*16+ihh)*32+iww  <- bufB[(dep*32+iww)*18 + ihh+1]
    for (int c = tid; c < NCELL; c += 256) {
        const int iww = c & 31;
        const int ihh = (c >> 5) & 15;
        const int dep = c >> 9;
        v2[(size_t)b * NCELL + c] = bufB[(dep * 32 + iww) * 18 + ihh + 1];
    }
}

// ---------------- K3: upsample broadcast ----------------
__global__ __launch_bounds__(256) void k_up(const float* __restrict__ v2,
                                            float* __restrict__ out)
{
    const int idx = blockIdx.x * 256 + threadIdx.x;     // 0 .. B*30720-1
    const int b   = idx / NQ;
    const int o   = idx - b * NQ;
    const int iw4 = o & 31;
    const int Hin = (o >> 5) & 63;
    const int Din = o >> 11;

    const float v = v2[(size_t)b * NCELL + ((Din / 3) * 16 + (Hin >> 2)) * 32 + iw4];
    *reinterpret_cast<float4*>(out + (size_t)b * NELEM + (size_t)o * 4) =
        make_float4(v, v, v, v);
}

extern "C" void kernel_launch(void* const* d_in, const int* in_sizes, int n_in,
                              void* d_out, int out_size, void* d_ws, size_t ws_size,
                              hipStream_t stream) {
    const float* x       = (const float*)d_in[0];
    const float* w_depth = (const float*)d_in[1];
    const float* b_depth = (const float*)d_in[2];
    const float* w_lon   = (const float*)d_in[3];
    const float* b_lon   = (const float*)d_in[4];
    const float* w_lat   = (const float*)d_in[5];
    const float* b_lat   = (const float*)d_in[6];
    float* out = (float*)d_out;

    const int Bn = in_sizes[0] / NELEM;   // 256

    float* ds = (float*)d_ws;                          // Bn*2560 floats
    float* v2 = ds + (size_t)Bn * NCELL;               // Bn*2560 floats

    k_down<<<dim3(Bn * NCELL / 256), dim3(256), 0, stream>>>(x, ds);
    k_conv<<<dim3(Bn), dim3(256), 0, stream>>>(ds, w_depth, b_depth,
                                               w_lon, b_lon, w_lat, b_lat, v2);
    k_up<<<dim3(Bn * NQ / 256), dim3(256), 0, stream>>>(v2, out);
}

// Round 3
// 247.087 us; speedup vs baseline: 1.0176x; 1.0124x over previous
//
#include <hip/hip_runtime.h>

// LocalNetwork, 4 wide kernels:
//  K1 k_down   : 3x4x4 mean downsample          (126 MB HBM read)
//  K2 k_depth  : depth conv3+relu, index-math gather  (tiny, L2/L3)
//  K3 k_lon    : lon conv3+relu, index-math gather    (tiny, L2/L3)
//  K4 k_lat_up : lat conv3+relu fused with broadcast upsample (126 MB HBM write)

#define NELEM (15 * 64 * 128)   // 122880 floats per batch item
#define NCELL 2560              // 5*16*32
#define LD    3584              // (5+2)*16*32
#define LLON  2720              // 5*16*(32+2)
#define LLAT  2880              // 5*(16+2)*32

// ---------------- K1: downsample ----------------
// ds[b][c], c = (id*16+ih)*32+iw
__global__ __launch_bounds__(256) void k_down(const float* __restrict__ x,
                                              float* __restrict__ ds)
{
    const int b  = blockIdx.y;
    const int c  = blockIdx.x * 256 + threadIdx.x;   // [0,2560)
    const int iw = c & 31;
    const int ih = (c >> 5) & 15;
    const int id = c >> 9;

    const float* p = x + (size_t)b * NELEM + ((id * 3) * 64 + ih * 4) * 128 + iw * 4;
    float s = 0.f;
    #pragma unroll
    for (int dd = 0; dd < 3; ++dd) {
        #pragma unroll
        for (int hh = 0; hh < 4; ++hh) {
            const float4 v = *reinterpret_cast<const float4*>(p + (dd * 64 + hh) * 128);
            s += (v.x + v.y) + (v.z + v.w);
        }
    }
    ds[(size_t)b * NCELL + c] = s * (1.f / 48.f);
}

// ---------------- K2: depth conv ----------------
// t_flat[f], f in [0,3584): k=f%7, q=f/7, ih=q&15, iw=q>>4;
// value = (1<=k<=5) ? ds[((k-1)*16+ih)*32+iw] : 0  (k=0,6 are depth pads)
__device__ __forceinline__ float tf_depth(const float* __restrict__ dsb, int f)
{
    const int k  = f % 7;
    const int q  = f / 7;
    const int ih = q & 15;
    const int iw = q >> 4;
    return (k >= 1 && k <= 5) ? dsb[((k - 1) * 16 + ih) * 32 + iw] : 0.f;
}

__global__ __launch_bounds__(256) void k_depth(const float* __restrict__ ds,
                                               const float* __restrict__ w,
                                               const float* __restrict__ bias,
                                               float* __restrict__ t1)
{
    const int b = blockIdx.y;
    const int l = blockIdx.x * 256 + threadIdx.x;    // [0,3584)
    const float* dsb = ds + (size_t)b * NCELL;

    const float x0 = (l > 0)      ? tf_depth(dsb, l - 1) : 0.f;
    const float x1 =                tf_depth(dsb, l);
    const float x2 = (l < LD - 1) ? tf_depth(dsb, l + 1) : 0.f;
    const float y  = w[l * 3] * x0 + w[l * 3 + 1] * x1 + w[l * 3 + 2] * x2 + bias[l];
    t1[(size_t)b * LD + l] = fmaxf(y, 0.f);
}

// ---------------- K3: lon conv ----------------
// u_flat[f], f in [0,2720): kw=f%34, q=f/34, ih=q&15, dep=q>>4;
// value = (1<=kw<=32) ? t1[((kw-1)*16+ih)*7 + dep+1] : 0
__device__ __forceinline__ float uf_lon(const float* __restrict__ t1b, int f)
{
    const int kw  = f % 34;
    const int q   = f / 34;
    const int ih  = q & 15;
    const int dep = q >> 4;
    return (kw >= 1 && kw <= 32) ? t1b[((kw - 1) * 16 + ih) * 7 + dep + 1] : 0.f;
}

__global__ __launch_bounds__(256) void k_lon(const float* __restrict__ t1,
                                             const float* __restrict__ w,
                                             const float* __restrict__ bias,
                                             float* __restrict__ u1)
{
    const int b = blockIdx.y;
    const int m = blockIdx.x * 256 + threadIdx.x;
    if (m >= LLON) return;
    const float* t1b = t1 + (size_t)b * LD;

    const float x0 = (m > 0)        ? uf_lon(t1b, m - 1) : 0.f;
    const float x1 =                  uf_lon(t1b, m);
    const float x2 = (m < LLON - 1) ? uf_lon(t1b, m + 1) : 0.f;
    const float y  = w[m * 3] * x0 + w[m * 3 + 1] * x1 + w[m * 3 + 2] * x2 + bias[m];
    u1[(size_t)b * LLON + m] = fmaxf(y, 0.f);
}

// ---------------- K4: lat conv + upsample ----------------
// v_flat[f], f in [0,2880): kh=f%18, q=f/18, iw=q&31, dep=q>>5;
// value = (1<=kh<=16) ? u1[(dep*16+kh-1)*34 + iw+1] : 0
__device__ __forceinline__ float vf_lat(const float* __restrict__ u1b, int f)
{
    const int kh  = f % 18;
    const int q   = f / 18;
    const int iw  = q & 31;
    const int dep = q >> 5;
    return (kh >= 1 && kh <= 16) ? u1b[(dep * 16 + kh - 1) * 34 + iw + 1] : 0.f;
}

__global__ __launch_bounds__(256) void k_lat_up(const float* __restrict__ u1,
                                                const float* __restrict__ w,
                                                const float* __restrict__ bias,
                                                float* __restrict__ out)
{
    const int b   = blockIdx.y;
    const int o   = blockIdx.x * 256 + threadIdx.x;  // [0,30720) float4 index
    const int iww = o & 31;
    const int Hin = (o >> 5) & 63;
    const int Din = o >> 11;
    const int dep = Din / 3;
    const int ihh = Hin >> 2;
    const int n   = (dep * 32 + iww) * 18 + ihh + 1;  // [1,2879]

    const float* u1b = u1 + (size_t)b * LLON;
    const float x0 = vf_lat(u1b, n - 1);
    const float x1 = vf_lat(u1b, n);
    const float x2 = vf_lat(u1b, n + 1);
    const float y  = fmaxf(w[n * 3] * x0 + w[n * 3 + 1] * x1 + w[n * 3 + 2] * x2 + bias[n], 0.f);

    *reinterpret_cast<float4*>(out + (size_t)b * NELEM + (size_t)o * 4) =
        make_float4(y, y, y, y);
}

extern "C" void kernel_launch(void* const* d_in, const int* in_sizes, int n_in,
                              void* d_out, int out_size, void* d_ws, size_t ws_size,
                              hipStream_t stream) {
    const float* x       = (const float*)d_in[0];
    const float* w_depth = (const float*)d_in[1];
    const float* b_depth = (const float*)d_in[2];
    const float* w_lon   = (const float*)d_in[3];
    const float* b_lon   = (const float*)d_in[4];
    const float* w_lat   = (const float*)d_in[5];
    const float* b_lat   = (const float*)d_in[6];
    float* out = (float*)d_out;

    const int Bn = in_sizes[0] / NELEM;   // 256

    float* ds = (float*)d_ws;                     // Bn*2560
    float* t1 = ds + (size_t)Bn * NCELL;          // Bn*3584
    float* u1 = t1 + (size_t)Bn * LD;             // Bn*2720

    k_down  <<<dim3(NCELL / 256, Bn), dim3(256), 0, stream>>>(x, ds);
    k_depth <<<dim3(LD / 256, Bn),    dim3(256), 0, stream>>>(ds, w_depth, b_depth, t1);
    k_lon   <<<dim3((LLON + 255) / 256, Bn), dim3(256), 0, stream>>>(t1, w_lon, b_lon, u1);
    k_lat_up<<<dim3(NELEM / 4 / 256, Bn), dim3(256), 0, stream>>>(u1, w_lat, b_lat, out);
}

// Round 4
// 242.016 us; speedup vs baseline: 1.0390x; 1.0210x over previous
//
#include <hip/hip_runtime.h>

// LocalNetwork, 3 kernels:
//  K1 k_down : 3x4x4 mean downsample                     (126 MB HBM read)
//  K2 k_mid  : depth conv3+relu fused into lon conv3+relu via recompute (L2-bound, tiny)
//  K3 k_vup  : lat conv3+relu + broadcast upsample, 1 thread per v     (126 MB HBM write)

#define NELEM (15 * 64 * 128)   // 122880 floats per batch item
#define NCELL 2560              // 5*16*32
#define LD    3584              // (5+2)*16*32
#define LLON  2720              // 5*16*(32+2)

// ---------------- K1: downsample ----------------
// ds[b][c], c = (id*16+ih)*32+iw
__global__ __launch_bounds__(256) void k_down(const float* __restrict__ x,
                                              float* __restrict__ ds)
{
    const int b  = blockIdx.y;
    const int c  = blockIdx.x * 256 + threadIdx.x;   // [0,2560)
    const int iw = c & 31;
    const int ih = (c >> 5) & 15;
    const int id = c >> 9;

    const float* p = x + (size_t)b * NELEM + ((id * 3) * 64 + ih * 4) * 128 + iw * 4;
    float s = 0.f;
    #pragma unroll
    for (int dd = 0; dd < 3; ++dd) {
        #pragma unroll
        for (int hh = 0; hh < 4; ++hh) {
            const float4 v = *reinterpret_cast<const float4*>(p + (dd * 64 + hh) * 128);
            s += (v.x + v.y) + (v.z + v.w);
        }
    }
    ds[(size_t)b * NCELL + c] = s * (1.f / 48.f);
}

// ---------------- depth-flat value (with pads) ----------------
// t_flat[f], f in [0,3584): k=f%7, q=f/7, ih=q&15, iw=q>>4;
// = (1<=k<=5) ? ds[((k-1)*16+ih)*32+iw] : 0
__device__ __forceinline__ float tf_depth(const float* __restrict__ dsb, int f)
{
    const int k  = f % 7;
    const int q  = f / 7;
    const int ih = q & 15;
    const int iw = q >> 4;
    return (k >= 1 && k <= 5) ? dsb[((k - 1) * 16 + ih) * 32 + iw] : 0.f;
}

// depth conv output t1[l], l in [0,3584), flat-boundary guards on l+-1
__device__ __forceinline__ float t1_val(const float* __restrict__ dsb,
                                        const float* __restrict__ wd,
                                        const float* __restrict__ bd, int l)
{
    const float x0 = (l > 0)      ? tf_depth(dsb, l - 1) : 0.f;
    const float x1 =                tf_depth(dsb, l);
    const float x2 = (l < LD - 1) ? tf_depth(dsb, l + 1) : 0.f;
    return fmaxf(wd[l * 3] * x0 + wd[l * 3 + 1] * x1 + wd[l * 3 + 2] * x2 + bd[l], 0.f);
}

// ---------------- K2: fused depth+lon conv ----------------
// u_flat[f], f in [0,2720): kw=f%34, q=f/34, ih=q&15, dep=q>>4;
// = (1<=kw<=32) ? t1[((kw-1)*16+ih)*7 + dep+1] : 0   (t1 index in [1,3582])
__device__ __forceinline__ float uf_lon(const float* __restrict__ dsb,
                                        const float* __restrict__ wd,
                                        const float* __restrict__ bd, int f)
{
    const int kw  = f % 34;
    const int q   = f / 34;
    const int ih  = q & 15;
    const int dep = q >> 4;
    if (kw < 1 || kw > 32) return 0.f;
    return t1_val(dsb, wd, bd, ((kw - 1) * 16 + ih) * 7 + dep + 1);
}

__global__ __launch_bounds__(256) void k_mid(const float* __restrict__ ds,
                                             const float* __restrict__ wd,
                                             const float* __restrict__ bd,
                                             const float* __restrict__ wl,
                                             const float* __restrict__ bl,
                                             float* __restrict__ u1)
{
    const int b = blockIdx.y;
    const int m = blockIdx.x * 256 + threadIdx.x;
    if (m >= LLON) return;
    const float* dsb = ds + (size_t)b * NCELL;

    const float x0 = (m > 0)        ? uf_lon(dsb, wd, bd, m - 1) : 0.f;
    const float x1 =                  uf_lon(dsb, wd, bd, m);
    const float x2 = (m < LLON - 1) ? uf_lon(dsb, wd, bd, m + 1) : 0.f;
    const float y  = wl[m * 3] * x0 + wl[m * 3 + 1] * x1 + wl[m * 3 + 2] * x2 + bl[m];
    u1[(size_t)b * LLON + m] = fmaxf(y, 0.f);
}

// ---------------- K3: lat conv + upsample, 1 thread per v ----------------
// v_flat[f], f in [0,2880): kh=f%18, q=f/18, iw=q&31, dep=q>>5;
// = (1<=kh<=16) ? u1[(dep*16+kh-1)*34 + iw+1] : 0
__device__ __forceinline__ float vf_lat(const float* __restrict__ u1b, int f)
{
    const int kh  = f % 18;
    const int q   = f / 18;
    const int iw  = q & 31;
    const int dep = q >> 5;
    return (kh >= 1 && kh <= 16) ? u1b[(dep * 16 + kh - 1) * 34 + iw + 1] : 0.f;
}

__global__ __launch_bounds__(256) void k_vup(const float* __restrict__ u1,
                                             const float* __restrict__ w,
                                             const float* __restrict__ bias,
                                             float* __restrict__ out)
{
    const int b   = blockIdx.y;
    const int c   = blockIdx.x * 256 + threadIdx.x;   // [0,2560): (dep*16+ihh)*32+iww
    const int iww = c & 31;
    const int ihh = (c >> 5) & 15;
    const int dep = c >> 9;
    const int n   = (dep * 32 + iww) * 18 + ihh + 1;  // [1,2879]

    const float* u1b = u1 + (size_t)b * LLON;
    const float x0 = vf_lat(u1b, n - 1);
    const float x1 = vf_lat(u1b, n);
    const float x2 = vf_lat(u1b, n + 1);
    const float y  = fmaxf(w[n * 3] * x0 + w[n * 3 + 1] * x1 + w[n * 3 + 2] * x2 + bias[n], 0.f);
    const float4 y4 = make_float4(y, y, y, y);

    // 12 replicas: D in {dep*3..+2}, H rows {ihh*4..+3}, one float4 in W
    float4* ob = reinterpret_cast<float4*>(out + (size_t)b * NELEM);
    #pragma unroll
    for (int dd = 0; dd < 3; ++dd) {
        #pragma unroll
        for (int hh = 0; hh < 4; ++hh) {
            ob[((dep * 3 + dd) * 64 + ihh * 4 + hh) * 32 + iww] = y4;
        }
    }
}

extern "C" void kernel_launch(void* const* d_in, const int* in_sizes, int n_in,
                              void* d_out, int out_size, void* d_ws, size_t ws_size,
                              hipStream_t stream) {
    const float* x       = (const float*)d_in[0];
    const float* w_depth = (const float*)d_in[1];
    const float* b_depth = (const float*)d_in[2];
    const float* w_lon   = (const float*)d_in[3];
    const float* b_lon   = (const float*)d_in[4];
    const float* w_lat   = (const float*)d_in[5];
    const float* b_lat   = (const float*)d_in[6];
    float* out = (float*)d_out;

    const int Bn = in_sizes[0] / NELEM;   // 256

    float* ds = (float*)d_ws;                     // Bn*2560
    float* u1 = ds + (size_t)Bn * NCELL;          // Bn*2720

    k_down<<<dim3(NCELL / 256, Bn), dim3(256), 0, stream>>>(x, ds);
    k_mid <<<dim3((LLON + 255) / 256, Bn), dim3(256), 0, stream>>>(ds, w_depth, b_depth,
                                                                   w_lon, b_lon, u1);
    k_vup <<<dim3(NCELL / 256, Bn), dim3(256), 0, stream>>>(u1, w_lat, b_lat, out);
}

// Round 5
// 231.149 us; speedup vs baseline: 1.0878x; 1.0470x over previous
//
#include <hip/hip_runtime.h>

// LocalNetwork, 2 kernels:
//  K1 k_down_mid : per (batch, ih): 3x4x4 mean downsample slice into LDS,
//                  then depth+lon conv3+relu fused -> u1    (126 MB HBM read)
//  K2 k_vup      : lat conv3+relu + broadcast upsample      (126 MB HBM write)

#define NELEM (15 * 64 * 128)   // 122880 floats per batch item
#define NCELL 2560              // 5*16*32
#define LD    3584              // (5+2)*16*32
#define LLON  2720              // 5*16*34

// ---- depth-flat value from LDS ds slice (this ih row) ----
// f = (iw*16+ih)*7 + k ; valid k in [1,5] -> lds[(k-1)*32 + iw]
__device__ __forceinline__ float tf_depth_lds(const float* __restrict__ lds, int f)
{
    const int k  = f % 7;
    const int q  = f / 7;
    const int iw = q >> 4;
    return (k >= 1 && k <= 5) ? lds[(k - 1) * 32 + iw] : 0.f;
}

// depth conv output t1[l]; for our uses l in [1,3582] so no flat-edge guards needed,
// and l+-1 pad crossings resolve to zeros inside tf_depth_lds.
__device__ __forceinline__ float t1_val_lds(const float* __restrict__ lds,
                                            const float* __restrict__ wd,
                                            const float* __restrict__ bd, int l)
{
    const float x0 = tf_depth_lds(lds, l - 1);
    const float x1 = tf_depth_lds(lds, l);
    const float x2 = tf_depth_lds(lds, l + 1);
    return fmaxf(wd[l * 3] * x0 + wd[l * 3 + 1] * x1 + wd[l * 3 + 2] * x2 + bd[l], 0.f);
}

// lon-padded flat value: f -> kw=f%34, q=f/34, dep=q>>4 (ih implicit = ours)
// kw in [1,32] -> t1 at ((kw-1)*16+ih)*7 + dep+1, else pad 0.
// (f at kw=0/33 pads covers the cross-row m+-1 cases too.)
__device__ __forceinline__ float uf_lon_lds(const float* __restrict__ lds,
                                            const float* __restrict__ wd,
                                            const float* __restrict__ bd,
                                            int f, int ih)
{
    const int kw  = f % 34;
    if (kw < 1 || kw > 32) return 0.f;
    const int dep = (f / 34) >> 4;
    return t1_val_lds(lds, wd, bd, ((kw - 1) * 16 + ih) * 7 + dep + 1);
}

// ---------------- K1: downsample + depth/lon conv ----------------
__global__ __launch_bounds__(256) void k_down_mid(const float* __restrict__ x,
                                                  const float* __restrict__ wd,
                                                  const float* __restrict__ bd,
                                                  const float* __restrict__ wl,
                                                  const float* __restrict__ bl,
                                                  float* __restrict__ u1)
{
    const int b   = blockIdx.y;
    const int ih  = blockIdx.x;          // [0,16)
    const int tid = threadIdx.x;

    __shared__ float ds[5 * 32];         // [id][iw] for this ih row

    // phase 1: 160 threads each reduce one 3x4x4 cell
    if (tid < 160) {
        const int iw = tid & 31;
        const int id = tid >> 5;
        const float* p = x + (size_t)b * NELEM + ((id * 3) * 64 + ih * 4) * 128 + iw * 4;
        float s = 0.f;
        #pragma unroll
        for (int dd = 0; dd < 3; ++dd) {
            #pragma unroll
            for (int hh = 0; hh < 4; ++hh) {
                const float4 v = *reinterpret_cast<const float4*>(p + (dd * 64 + hh) * 128);
                s += (v.x + v.y) + (v.z + v.w);
            }
        }
        ds[id * 32 + iw] = s * (1.f / 48.f);
    }
    __syncthreads();

    // phase 2: 170 threads each compute one u1 value of this ih row
    if (tid < 170) {
        const int kw  = tid % 34;
        const int dep = tid / 34;
        const int m   = (dep * 16 + ih) * 34 + kw;   // global lon-flat index

        const float x0 = (m > 0)        ? uf_lon_lds(ds, wd, bd, m - 1, ih) : 0.f;
        const float x1 =                  uf_lon_lds(ds, wd, bd, m,     ih);
        const float x2 = (m < LLON - 1) ? uf_lon_lds(ds, wd, bd, m + 1, ih) : 0.f;
        const float y  = wl[m * 3] * x0 + wl[m * 3 + 1] * x1 + wl[m * 3 + 2] * x2 + bl[m];
        u1[(size_t)b * LLON + m] = fmaxf(y, 0.f);
    }
}

// ---------------- K2: lat conv + upsample, 1 thread per v ----------------
// v_flat[f]: kh=f%18, q=f/18, iw=q&31, dep=q>>5;
// = (1<=kh<=16) ? u1[(dep*16+kh-1)*34 + iw+1] : 0
__device__ __forceinline__ float vf_lat(const float* __restrict__ u1b, int f)
{
    const int kh  = f % 18;
    const int q   = f / 18;
    const int iw  = q & 31;
    const int dep = q >> 5;
    return (kh >= 1 && kh <= 16) ? u1b[(dep * 16 + kh - 1) * 34 + iw + 1] : 0.f;
}

__global__ __launch_bounds__(256) void k_vup(const float* __restrict__ u1,
                                             const float* __restrict__ w,
                                             const float* __restrict__ bias,
                                             float* __restrict__ out)
{
    const int b   = blockIdx.y;
    const int c   = blockIdx.x * 256 + threadIdx.x;   // [0,2560): (dep*16+ihh)*32+iww
    const int iww = c & 31;
    const int ihh = (c >> 5) & 15;
    const int dep = c >> 9;
    const int n   = (dep * 32 + iww) * 18 + ihh + 1;  // [1,2879]

    const float* u1b = u1 + (size_t)b * LLON;
    const float x0 = vf_lat(u1b, n - 1);
    const float x1 = vf_lat(u1b, n);
    const float x2 = vf_lat(u1b, n + 1);
    const float y  = fmaxf(w[n * 3] * x0 + w[n * 3 + 1] * x1 + w[n * 3 + 2] * x2 + bias[n], 0.f);
    const float4 y4 = make_float4(y, y, y, y);

    float4* ob = reinterpret_cast<float4*>(out + (size_t)b * NELEM);
    #pragma unroll
    for (int dd = 0; dd < 3; ++dd) {
        #pragma unroll
        for (int hh = 0; hh < 4; ++hh) {
            ob[((dep * 3 + dd) * 64 + ihh * 4 + hh) * 32 + iww] = y4;
        }
    }
}

extern "C" void kernel_launch(void* const* d_in, const int* in_sizes, int n_in,
                              void* d_out, int out_size, void* d_ws, size_t ws_size,
                              hipStream_t stream) {
    const float* x       = (const float*)d_in[0];
    const float* w_depth = (const float*)d_in[1];
    const float* b_depth = (const float*)d_in[2];
    const float* w_lon   = (const float*)d_in[3];
    const float* b_lon   = (const float*)d_in[4];
    const float* w_lat   = (const float*)d_in[5];
    const float* b_lat   = (const float*)d_in[6];
    float* out = (float*)d_out;

    const int Bn = in_sizes[0] / NELEM;   // 256

    float* u1 = (float*)d_ws;             // Bn*2720 floats

    k_down_mid<<<dim3(16, Bn), dim3(256), 0, stream>>>(x, w_depth, b_depth,
                                                       w_lon, b_lon, u1);
    k_vup     <<<dim3(NCELL / 256, Bn), dim3(256), 0, stream>>>(u1, w_lat, b_lat, out);
}